// Round 11
// baseline (513.038 us; speedup 1.0000x reference)
//
#include <hip/hip_runtime.h>
#include <hip/hip_bf16.h>
#include <math.h>

#define NN 50000
#define EE 800000
#define EPE 850000   // EE + NN self loops
#define HCC 128
#define GGR 256
#define NHIDD 512
#define NOUTD 768
#define SCAN_NBLK ((NN + 1023) / 1024)   // 49
#define MBLK ((NN + 63) / 64)            // 782
#define NPAD 50176                        // counts replica stride (64B aligned)
#define NREP 8
#define NPART (NN / 8)                    // 6250 dst per partition

typedef __attribute__((ext_vector_type(8))) short bf16x8;
typedef __attribute__((ext_vector_type(4))) float f32x4;

__device__ __forceinline__ void atomicMaxF(float* addr, float v) {
    if (v >= 0.f) atomicMax(reinterpret_cast<int*>(addr), __float_as_int(v));
    else atomicMin(reinterpret_cast<unsigned int*>(addr), __float_as_uint(v));
}

__device__ __forceinline__ float lrelu(float x) { return x > 0.f ? x : 0.2f * x; }

__device__ __forceinline__ ushort f2bf(float f) {
    unsigned u = __float_as_uint(f);
    unsigned r = (u + 0x7fffu + ((u >> 16) & 1u)) >> 16;   // RNE
    return (ushort)r;
}
__device__ __forceinline__ float bf2f(ushort b) {
    return __uint_as_float(((unsigned)b) << 16);
}

__device__ __forceinline__ float sel4(int k, float a0, float a1, float a2, float a3) {
    float lo = (k & 1) ? a1 : a0;
    float hi = (k & 1) ? a3 : a2;
    return (k & 2) ? hi : lo;
}

// ---------------- converts ----------------
__global__ void conv_x(const float* __restrict__ X, ushort* __restrict__ Xb) {
    int i = blockIdx.x * 256 + threadIdx.x;
    if (i < NN * HCC / 4) {
        float4 v = reinterpret_cast<const float4*>(X)[i];
        ushort4 o;
        o.x = f2bf(v.x); o.y = f2bf(v.y); o.z = f2bf(v.z); o.w = f2bf(v.w);
        reinterpret_cast<ushort4*>(Xb)[i] = o;
    }
}

__global__ void conv_w(const float* __restrict__ W, const float* __restrict__ SKW,
                       ushort* __restrict__ Wt) {
    int i = blockIdx.x * 256 + threadIdx.x;
    if (i >= 256 * 128) return;
    int n = i >> 7, k = i & 127;
    float v = (n < 128) ? W[(size_t)k * 128 + n] : SKW[(size_t)k * 128 + (n - 128)];
    Wt[i] = f2bf(v);
}

// ---------------- CSR build ----------------
__global__ void hist_zero8(int* __restrict__ cnt8) {
    int i = blockIdx.x * 256 + threadIdx.x;
    if (i < NREP * NPAD) cnt8[i] = 0;
}

__global__ void hist8(const int* __restrict__ ei, int* __restrict__ cnt8) {
    int e = blockIdx.x * 256 + threadIdx.x;
    if (e >= EPE) return;
    int rep = blockIdx.x & 7;
    int d = (e < EE) ? ei[EE + e] : e - EE;
    atomicAdd(&cnt8[rep * NPAD + d], 1);
}

__global__ __launch_bounds__(256) void scan_partial(const int* __restrict__ cnt8,
                                                    int* __restrict__ excl,
                                                    int* __restrict__ blocksums)
{
    __shared__ int s[256];
    const int b = blockIdx.x, t = threadIdx.x;
    const int idx = b * 1024 + t * 4;
    int a[4] = {0, 0, 0, 0};
    #pragma unroll
    for (int j = 0; j < 4; ++j) {
        if (idx + j < NN) {
            int tot = 0;
            #pragma unroll
            for (int r = 0; r < NREP; ++r) tot += cnt8[r * NPAD + idx + j];
            a[j] = tot;
        }
    }
    int sum4 = a[0] + a[1] + a[2] + a[3];
    s[t] = sum4;
    __syncthreads();
    #pragma unroll
    for (int off = 1; off < 256; off <<= 1) {
        int add = (t >= off) ? s[t - off] : 0;
        __syncthreads();
        s[t] += add;
        __syncthreads();
    }
    int e0 = s[t] - sum4;
    if (idx + 0 < NN) excl[idx + 0] = e0;
    if (idx + 1 < NN) excl[idx + 1] = e0 + a[0];
    if (idx + 2 < NN) excl[idx + 2] = e0 + a[0] + a[1];
    if (idx + 3 < NN) excl[idx + 3] = e0 + a[0] + a[1] + a[2];
    if (t == 255) blocksums[b] = s[255];
}

__global__ __launch_bounds__(64) void scan_sums(int* __restrict__ blocksums,
                                                int* __restrict__ blockoffs,
                                                int* __restrict__ row_start)
{
    __shared__ int s[64];
    int t = threadIdx.x;
    int v = (t < SCAN_NBLK) ? blocksums[t] : 0;
    s[t] = v;
    __syncthreads();
    #pragma unroll
    for (int off = 1; off < 64; off <<= 1) {
        int add = (t >= off) ? s[t - off] : 0;
        __syncthreads();
        s[t] += add;
        __syncthreads();
    }
    if (t < SCAN_NBLK) blockoffs[t] = s[t] - v;
    if (t == 63) row_start[NN] = s[63];
}

__global__ void scan_add(const int* __restrict__ excl, const int* __restrict__ blockoffs,
                         int* __restrict__ row_start, int* __restrict__ cursor)
{
    int i = blockIdx.x * 256 + threadIdx.x;
    if (i >= NN) return;
    int v = excl[i] + blockoffs[i >> 10];
    row_start[i] = v;
    cursor[i] = v;
}

// dst-range-partitioned scatter (single-XCD cursor/csr lines per partition)
__global__ __launch_bounds__(256) void scatter_part(const int* __restrict__ ei,
                                                    int* __restrict__ cursor,
                                                    int* __restrict__ csr_src)
{
    const int p = blockIdx.x & 7;
    const int q = blockIdx.x >> 3;
    const int nq = gridDim.x >> 3;
    const int lo = p * NPART, hi = lo + NPART;
    const int stride = nq * 256;
    for (int e = q * 256 + threadIdx.x; e < EE; e += stride) {
        int d = ei[EE + e];
        if (d >= lo && d < hi) {
            int s = ei[e];
            int pos = atomicAdd(&cursor[d], 1);
            csr_src[pos] = s;
        }
    }
    for (int i = q * 256 + threadIdx.x; i < NPART; i += stride) {
        int d = lo + i;
        int pos = atomicAdd(&cursor[d], 1);
        csr_src[pos] = d;
    }
}

// ---------------- MFMA node GEMM + fused attention coefficients ----------------
__global__ __launch_bounds__(256) void gemm_mfma(
    const ushort* __restrict__ Xb,   // [NN][128] bf16
    const ushort* __restrict__ Wt,   // [256][128] bf16
    const float* __restrict__ skb, const float* __restrict__ bb,
    const float* __restrict__ as_, const float* __restrict__ ad_,
    ushort* __restrict__ Hout, float* __restrict__ Agg,
    float* __restrict__ esrc, float* __restrict__ edst)
{
    __shared__ ushort Xs[64 * 128];          // 16 KB, XOR-swizzled rows
    __shared__ float sh_es[64][4], sh_ed[64][4];
    const int r0 = blockIdx.x * 64;
    const int tid = threadIdx.x;
    const int w = tid >> 6;
    const int l = tid & 63;
    const int lm = l & 15;
    const int lk = l >> 4;

    #pragma unroll
    for (int it = 0; it < 4; ++it) {
        int slot = it * 256 + tid;
        int row = slot >> 4;
        int bc = (slot & 15) << 4;
        int n = r0 + row;
        bf16x8 v = (bf16x8)(short)0;
        if (n < NN) v = *reinterpret_cast<const bf16x8*>(Xb + (size_t)n * 128 + (bc >> 1));
        *reinterpret_cast<bf16x8*>(reinterpret_cast<char*>(Xs) + row * 256 + (bc ^ ((row & 7) << 4))) = v;
    }
    __syncthreads();

    f32x4 acc[4][4];
    #pragma unroll
    for (int nb = 0; nb < 4; ++nb)
        #pragma unroll
        for (int rf = 0; rf < 4; ++rf)
            acc[nb][rf] = (f32x4){0.f, 0.f, 0.f, 0.f};

    #pragma unroll
    for (int ks = 0; ks < 4; ++ks) {
        bf16x8 a[4];
        #pragma unroll
        for (int rf = 0; rf < 4; ++rf) {
            int row = rf * 16 + lm;
            int bc = (ks * 32 + lk * 8) * 2;
            a[rf] = *reinterpret_cast<const bf16x8*>(
                reinterpret_cast<const char*>(Xs) + row * 256 + (bc ^ ((row & 7) << 4)));
        }
        #pragma unroll
        for (int nb = 0; nb < 4; ++nb) {
            int ncol = (w * 4 + nb) * 16 + lm;
            bf16x8 b = *reinterpret_cast<const bf16x8*>(Wt + (size_t)ncol * 128 + ks * 32 + lk * 8);
            #pragma unroll
            for (int rf = 0; rf < 4; ++rf)
                acc[nb][rf] = __builtin_amdgcn_mfma_f32_16x16x32_bf16(a[rf], b, acc[nb][rf], 0, 0, 0);
        }
    }

    if (w < 2) {
        float asv[4], adv[4];
        #pragma unroll
        for (int nb = 0; nb < 4; ++nb) {
            int ncol = (w * 4 + nb) * 16 + lm;
            asv[nb] = as_[ncol];
            adv[nb] = ad_[ncol];
        }
        #pragma unroll
        for (int rf = 0; rf < 4; ++rf) {
            #pragma unroll
            for (int r = 0; r < 4; ++r) {
                int nl = rf * 16 + lk * 4 + r;
                int n = r0 + nl;
                float es0 = 0.f, es1 = 0.f, ed0 = 0.f, ed1 = 0.f;
                #pragma unroll
                for (int nb = 0; nb < 4; ++nb) {
                    float v = acc[nb][rf][r];
                    int ncol = (w * 4 + nb) * 16 + lm;
                    if (n < NN) Hout[(size_t)n * 128 + ncol] = f2bf(v);
                    if (nb < 2) { es0 = fmaf(v, asv[nb], es0); ed0 = fmaf(v, adv[nb], ed0); }
                    else        { es1 = fmaf(v, asv[nb], es1); ed1 = fmaf(v, adv[nb], ed1); }
                }
                #pragma unroll
                for (int m = 1; m < 16; m <<= 1) {
                    es0 += __shfl_xor(es0, m); ed0 += __shfl_xor(ed0, m);
                    es1 += __shfl_xor(es1, m); ed1 += __shfl_xor(ed1, m);
                }
                if (lm == 0) {
                    sh_es[nl][w * 2 + 0] = es0; sh_ed[nl][w * 2 + 0] = ed0;
                    sh_es[nl][w * 2 + 1] = es1; sh_ed[nl][w * 2 + 1] = ed1;
                }
            }
        }
    } else {
        #pragma unroll
        for (int nb = 0; nb < 4; ++nb) {
            int ncol = (w * 4 + nb) * 16 + lm;
            int c = ncol - 128;
            #pragma unroll
            for (int rf = 0; rf < 4; ++rf) {
                #pragma unroll
                for (int r = 0; r < 4; ++r) {
                    int n = r0 + rf * 16 + lk * 4 + r;
                    if (n >= NN) continue;
                    Agg[(size_t)n * 128 + c] = acc[nb][rf][r] + skb[c] + bb[c];
                }
            }
        }
    }
    __syncthreads();
    if (tid < 256) {
        int nl = tid >> 2, hd = tid & 3;
        int n = r0 + nl;
        if (n < NN) {
            esrc[n * 4 + hd] = sh_es[nl][hd];
            edst[n * 4 + hd] = sh_ed[nl][hd];
        }
    }
}

// ---------------- per-dst GAT: one wave per node, no LDS, no barriers ----------------
// phase1: lane l owns edge base+l -> 4 head logits in regs; 64-wide shfl_xor
// online softmax. phase2: lanes = 4 edge-slots x 16 channel-groups; weights/src
// shuffled from owning lane; slot partials combined by shfl_xor(16/32).
__global__ __launch_bounds__(256) void gat_aggr_wave(
    const int* __restrict__ row_start, const int* __restrict__ csr_src,
    const float* __restrict__ esrc, const float* __restrict__ edst,
    const ushort* __restrict__ Hb, const float* __restrict__ skipagg,
    ushort* __restrict__ outbuf)
{
    const int t = threadIdx.x;
    const int d = blockIdx.x * 4 + (t >> 6);
    if (d >= NN) return;
    const int l = t & 63;
    const int slot = l >> 4;           // 0..3
    const int cg = l & 15;
    const int c0 = cg * 8;
    const int ghd = cg >> 2;
    const int r0 = row_start[d], r1 = row_start[d + 1];
    const float4 edv = *reinterpret_cast<const float4*>(edst + (size_t)d * 4);

    float acc[8] = {0.f, 0.f, 0.f, 0.f, 0.f, 0.f, 0.f, 0.f};
    float m0 = -INFINITY, m1 = -INFINITY, m2 = -INFINITY, m3 = -INFINITY;
    float z0 = 0.f, z1 = 0.f, z2 = 0.f, z3 = 0.f;

    for (int base = r0; base < r1; base += 64) {
        const int nc = min(64, r1 - base);
        // ---- phase 1: logits for this lane's edge ----
        int sreg = 0;
        float g0 = -INFINITY, g1 = -INFINITY, g2 = -INFINITY, g3 = -INFINITY;
        if (l < nc) {
            sreg = csr_src[base + l];
            float4 ev = *reinterpret_cast<const float4*>(esrc + (size_t)sreg * 4);
            g0 = lrelu(ev.x + edv.x);
            g1 = lrelu(ev.y + edv.y);
            g2 = lrelu(ev.z + edv.z);
            g3 = lrelu(ev.w + edv.w);
        }
        float x0 = fmaxf(m0, g0), x1 = fmaxf(m1, g1), x2 = fmaxf(m2, g2), x3 = fmaxf(m3, g3);
        #pragma unroll
        for (int off = 1; off < 64; off <<= 1) {
            x0 = fmaxf(x0, __shfl_xor(x0, off));
            x1 = fmaxf(x1, __shfl_xor(x1, off));
            x2 = fmaxf(x2, __shfl_xor(x2, off));
            x3 = fmaxf(x3, __shfl_xor(x3, off));
        }
        float sc0 = __expf(m0 - x0), sc1 = __expf(m1 - x1);
        float sc2 = __expf(m2 - x2), sc3 = __expf(m3 - x3);
        float w0 = __expf(g0 - x0), w1 = __expf(g1 - x1);
        float w2 = __expf(g2 - x2), w3 = __expf(g3 - x3);
        float p0 = w0, p1 = w1, p2 = w2, p3 = w3;
        #pragma unroll
        for (int off = 1; off < 64; off <<= 1) {
            p0 += __shfl_xor(p0, off);
            p1 += __shfl_xor(p1, off);
            p2 += __shfl_xor(p2, off);
            p3 += __shfl_xor(p3, off);
        }
        z0 = z0 * sc0 + p0; z1 = z1 * sc1 + p1;
        z2 = z2 * sc2 + p2; z3 = z3 * sc3 + p3;
        m0 = x0; m1 = x1; m2 = x2; m3 = x3;
        // ---- phase 2: gather (4 edges per iteration across slots) ----
        float scg = sel4(ghd, sc0, sc1, sc2, sc3);
        #pragma unroll
        for (int j = 0; j < 8; ++j) acc[j] *= scg;
        for (int i0 = 0; i0 < nc; i0 += 4) {
            int e = i0 + slot;
            int s_e = __shfl(sreg, e);
            float u0 = __shfl(w0, e), u1 = __shfl(w1, e);
            float u2 = __shfl(w2, e), u3 = __shfl(w3, e);
            if (e < nc) {
                float wgt = sel4(ghd, u0, u1, u2, u3);
                bf16x8 row = *reinterpret_cast<const bf16x8*>(Hb + (size_t)s_e * 128 + c0);
                #pragma unroll
                for (int j = 0; j < 8; ++j)
                    acc[j] = fmaf(wgt, bf2f((ushort)row[j]), acc[j]);
            }
        }
    }
    // combine slot partials
    #pragma unroll
    for (int j = 0; j < 8; ++j) {
        acc[j] += __shfl_xor(acc[j], 16);
        acc[j] += __shfl_xor(acc[j], 32);
    }
    if (slot == 0) {
        float zi = 1.f / sel4(ghd, z0, z1, z2, z3);
        ushort4 o0, o1;
        const float* sk = skipagg + (size_t)d * 128 + c0;
        o0.x = f2bf(fmaxf(sk[0] + acc[0] * zi, 0.f));
        o0.y = f2bf(fmaxf(sk[1] + acc[1] * zi, 0.f));
        o0.z = f2bf(fmaxf(sk[2] + acc[2] * zi, 0.f));
        o0.w = f2bf(fmaxf(sk[3] + acc[3] * zi, 0.f));
        o1.x = f2bf(fmaxf(sk[4] + acc[4] * zi, 0.f));
        o1.y = f2bf(fmaxf(sk[5] + acc[5] * zi, 0.f));
        o1.z = f2bf(fmaxf(sk[6] + acc[6] * zi, 0.f));
        o1.w = f2bf(fmaxf(sk[7] + acc[7] * zi, 0.f));
        *reinterpret_cast<ushort4*>(outbuf + (size_t)d * 128 + c0) = o0;
        *reinterpret_cast<ushort4*>(outbuf + (size_t)d * 128 + c0 + 4) = o1;
    }
}

// ---------------- pooling + MLP ----------------
__global__ void pool_init(float* __restrict__ pooled) {
    int i = blockIdx.x * 256 + threadIdx.x;
    if (i < GGR * HCC) pooled[i] = -INFINITY;
}

__global__ __launch_bounds__(256) void pool_max_sorted(
    const ushort* __restrict__ xf, const int* __restrict__ batch,
    float* __restrict__ pooled)
{
    __shared__ int gb[32];
    const int n0 = blockIdx.x * 32;
    const int t = threadIdx.x;
    if (t < 32) gb[t] = (n0 + t < NN) ? batch[n0 + t] : -1;
    __syncthreads();
    const int c = t & 127;
    const int half = t >> 7;
    int curg = -1;
    float curv = -INFINITY;
    #pragma unroll 4
    for (int i = 0; i < 16; ++i) {
        int n = n0 + half * 16 + i;
        if (n >= NN) break;
        int g = gb[half * 16 + i];
        float v = bf2f(xf[(size_t)n * 128 + c]);
        if (g != curg) {
            if (curg >= 0) atomicMaxF(&pooled[curg * 128 + c], curv);
            curg = g; curv = v;
        } else {
            curv = fmaxf(curv, v);
        }
    }
    if (curg >= 0) atomicMaxF(&pooled[curg * 128 + c], curv);
}

__global__ __launch_bounds__(512) void mlp1(const float* __restrict__ pooled,
                                            const float* __restrict__ w,
                                            const float* __restrict__ bias,
                                            float* __restrict__ hid)
{
    __shared__ float xs[128];
    int g = blockIdx.x, t = threadIdx.x;
    if (t < 128) {
        float v = pooled[g * 128 + t];
        if (!isfinite(v)) v = 0.f;
        xs[t] = v;
    }
    __syncthreads();
    float acc = 0.f;
    #pragma unroll 8
    for (int k = 0; k < 128; ++k) acc += xs[k] * w[(size_t)k * NHIDD + t];
    hid[(size_t)g * NHIDD + t] = fmaxf(acc + bias[t], 0.f);
}

__global__ __launch_bounds__(768) void mlp2(const float* __restrict__ hid,
                                            const float* __restrict__ w,
                                            const float* __restrict__ bias,
                                            float* __restrict__ out)
{
    __shared__ float xs[NHIDD];
    int g = blockIdx.x, t = threadIdx.x;
    if (t < NHIDD) xs[t] = hid[(size_t)g * NHIDD + t];
    __syncthreads();
    float acc = 0.f;
    #pragma unroll 8
    for (int k = 0; k < NHIDD; ++k) acc += xs[k] * w[(size_t)k * NOUTD + t];
    out[(size_t)g * NOUTD + t] = acc + bias[t];
}

extern "C" void kernel_launch(void* const* d_in, const int* in_sizes, int n_in,
                              void* d_out, int out_size, void* d_ws, size_t ws_size,
                              hipStream_t stream)
{
    const float* x = (const float*)d_in[0];
    const int* ei = (const int*)d_in[1];
    const int* batch = (const int*)d_in[2];
    const float* W[3]   = {(const float*)d_in[3],  (const float*)d_in[9],  (const float*)d_in[15]};
    const float* AS[3]  = {(const float*)d_in[4],  (const float*)d_in[10], (const float*)d_in[16]};
    const float* AD[3]  = {(const float*)d_in[5],  (const float*)d_in[11], (const float*)d_in[17]};
    const float* B[3]   = {(const float*)d_in[6],  (const float*)d_in[12], (const float*)d_in[18]};
    const float* SKW[3] = {(const float*)d_in[7],  (const float*)d_in[13], (const float*)d_in[19]};
    const float* SKB[3] = {(const float*)d_in[8],  (const float*)d_in[14], (const float*)d_in[20]};
    const float* m1w = (const float*)d_in[21];
    const float* m1b = (const float*)d_in[22];
    const float* m2w = (const float*)d_in[23];
    const float* m2b = (const float*)d_in[24];
    float* out = (float*)d_out;

    float* p = (float*)d_ws;
    ushort* bufA = (ushort*)p; p += (size_t)NN * HCC / 2;
    ushort* bufB = (ushort*)p; p += (size_t)NN * HCC / 2;
    ushort* xb   = (ushort*)p; p += (size_t)NN * HCC / 2;
    ushort* hbuf = (ushort*)p; p += (size_t)NN * HCC / 2;
    ushort* wt3  = (ushort*)p; p += 3 * 256 * 128 / 2;
    float* agg  = p; p += (size_t)NN * HCC;
    float* esrc = p; p += NN * 4;
    float* edst = p; p += NN * 4;
    float* pooled = p; p += GGR * HCC;
    float* hidden = p; p += GGR * NHIDD;
    int* cnt8      = (int*)p; p += NREP * NPAD;
    int* cursor    = (int*)p; p += NN;
    int* excl      = (int*)p; p += NN;
    int* row_start = (int*)p; p += NN + 4;
    int* csr_src   = (int*)p; p += EPE;
    int* blocksums = (int*)p; p += 64;
    int* blockoffs = (int*)p; p += 64;

    conv_x<<<(NN * HCC / 4 + 255) / 256, 256, 0, stream>>>(x, xb);
    for (int l = 0; l < 3; ++l)
        conv_w<<<(256 * 128 + 255) / 256, 256, 0, stream>>>(W[l], SKW[l], wt3 + l * 256 * 128);

    hist_zero8<<<(NREP * NPAD + 255) / 256, 256, 0, stream>>>(cnt8);
    hist8<<<(EPE + 255) / 256, 256, 0, stream>>>(ei, cnt8);
    scan_partial<<<SCAN_NBLK, 256, 0, stream>>>(cnt8, excl, blocksums);
    scan_sums<<<1, 64, 0, stream>>>(blocksums, blockoffs, row_start);
    scan_add<<<(NN + 255) / 256, 256, 0, stream>>>(excl, blockoffs, row_start, cursor);
    scatter_part<<<1024, 256, 0, stream>>>(ei, cursor, csr_src);

    const ushort* cur = xb;
    ushort* outs[3] = {bufA, bufB, bufA};
    for (int l = 0; l < 3; ++l) {
        gemm_mfma<<<MBLK, 256, 0, stream>>>(cur, wt3 + l * 256 * 128, SKB[l], B[l],
                                            AS[l], AD[l], hbuf, agg, esrc, edst);
        gat_aggr_wave<<<(NN + 3) / 4, 256, 0, stream>>>(row_start, csr_src, esrc, edst,
                                                        hbuf, agg, outs[l]);
        cur = outs[l];
    }
    pool_init<<<(GGR * HCC) / 256, 256, 0, stream>>>(pooled);
    pool_max_sorted<<<(NN + 31) / 32, 256, 0, stream>>>(cur, batch, pooled);
    mlp1<<<GGR, NHIDD, 0, stream>>>(pooled, m1w, m1b, hidden);
    mlp2<<<GGR, NOUTD, 0, stream>>>(hidden, m2w, m2b, out);
}

// Round 12
// 492.494 us; speedup vs baseline: 1.0417x; 1.0417x over previous
//
#include <hip/hip_runtime.h>
#include <hip/hip_bf16.h>
#include <math.h>

#define NN 50000
#define EE 800000
#define EPE 850000   // EE + NN self loops
#define HCC 128
#define GGR 256
#define NHIDD 512
#define NOUTD 768
#define CHUNK 256
#define CPAD (CHUNK + 8)
#define SCAN_NBLK ((NN + 1023) / 1024)   // 49
#define MBLK ((NN + 63) / 64)            // 782
#define NPAD 50176                        // counts replica stride (64B aligned)
#define NREP 8
#define NPART (NN / 8)                    // 6250 dst per partition

typedef __attribute__((ext_vector_type(8))) short bf16x8;
typedef __attribute__((ext_vector_type(4))) float f32x4;

__device__ __forceinline__ void atomicMaxF(float* addr, float v) {
    if (v >= 0.f) atomicMax(reinterpret_cast<int*>(addr), __float_as_int(v));
    else atomicMin(reinterpret_cast<unsigned int*>(addr), __float_as_uint(v));
}

__device__ __forceinline__ float lrelu(float x) { return x > 0.f ? x : 0.2f * x; }

__device__ __forceinline__ ushort f2bf(float f) {
    unsigned u = __float_as_uint(f);
    unsigned r = (u + 0x7fffu + ((u >> 16) & 1u)) >> 16;   // RNE
    return (ushort)r;
}
__device__ __forceinline__ float bf2f(ushort b) {
    return __uint_as_float(((unsigned)b) << 16);
}

// ---------------- fused prep: conv_x + 3x conv_w + hist_zero + pool_init ----------------
#define PB_X 6250                   // NN*HCC/4 / 256
#define PB_W 128                    // 256*128/256
#define PB_C 1568                   // NREP*NPAD/256
#define PB_P 128                    // GGR*HCC/256
#define PREP_BLOCKS (PB_X + 3 * PB_W + PB_C + PB_P)

__global__ __launch_bounds__(256) void prep(
    const float* __restrict__ X, ushort* __restrict__ Xb,
    const float* __restrict__ W0, const float* __restrict__ SKW0,
    const float* __restrict__ W1, const float* __restrict__ SKW1,
    const float* __restrict__ W2, const float* __restrict__ SKW2,
    ushort* __restrict__ wt3, int* __restrict__ cnt8, float* __restrict__ pooled)
{
    int b = blockIdx.x;
    int t = threadIdx.x;
    if (b < PB_X) {
        int i = b * 256 + t;
        float4 v = reinterpret_cast<const float4*>(X)[i];
        ushort4 o;
        o.x = f2bf(v.x); o.y = f2bf(v.y); o.z = f2bf(v.z); o.w = f2bf(v.w);
        reinterpret_cast<ushort4*>(Xb)[i] = o;
        return;
    }
    b -= PB_X;
    if (b < 3 * PB_W) {
        int l = b / PB_W;
        int i = (b % PB_W) * 256 + t;
        int n = i >> 7, k = i & 127;
        const float* W = (l == 0) ? W0 : (l == 1) ? W1 : W2;
        const float* SKW = (l == 0) ? SKW0 : (l == 1) ? SKW1 : SKW2;
        float v = (n < 128) ? W[(size_t)k * 128 + n] : SKW[(size_t)k * 128 + (n - 128)];
        wt3[l * 256 * 128 + i] = f2bf(v);
        return;
    }
    b -= 3 * PB_W;
    if (b < PB_C) {
        int i = b * 256 + t;
        if (i < NREP * NPAD) cnt8[i] = 0;
        return;
    }
    b -= PB_C;
    {
        int i = b * 256 + t;
        if (i < GGR * HCC) pooled[i] = -INFINITY;
    }
}

// ---------------- CSR build ----------------
__global__ void hist8(const int* __restrict__ ei, int* __restrict__ cnt8) {
    int e = blockIdx.x * 256 + threadIdx.x;
    if (e >= EPE) return;
    int rep = blockIdx.x & 7;
    int d = (e < EE) ? ei[EE + e] : e - EE;
    atomicAdd(&cnt8[rep * NPAD + d], 1);
}

__global__ __launch_bounds__(256) void scan_partial(const int* __restrict__ cnt8,
                                                    int* __restrict__ excl,
                                                    int* __restrict__ blocksums)
{
    __shared__ int s[256];
    const int b = blockIdx.x, t = threadIdx.x;
    const int idx = b * 1024 + t * 4;
    int a[4] = {0, 0, 0, 0};
    #pragma unroll
    for (int j = 0; j < 4; ++j) {
        if (idx + j < NN) {
            int tot = 0;
            #pragma unroll
            for (int r = 0; r < NREP; ++r) tot += cnt8[r * NPAD + idx + j];
            a[j] = tot;
        }
    }
    int sum4 = a[0] + a[1] + a[2] + a[3];
    s[t] = sum4;
    __syncthreads();
    #pragma unroll
    for (int off = 1; off < 256; off <<= 1) {
        int add = (t >= off) ? s[t - off] : 0;
        __syncthreads();
        s[t] += add;
        __syncthreads();
    }
    int e0 = s[t] - sum4;
    if (idx + 0 < NN) excl[idx + 0] = e0;
    if (idx + 1 < NN) excl[idx + 1] = e0 + a[0];
    if (idx + 2 < NN) excl[idx + 2] = e0 + a[0] + a[1];
    if (idx + 3 < NN) excl[idx + 3] = e0 + a[0] + a[1] + a[2];
    if (t == 255) blocksums[b] = s[255];
}

__global__ __launch_bounds__(64) void scan_sums(int* __restrict__ blocksums,
                                                int* __restrict__ blockoffs,
                                                int* __restrict__ row_start)
{
    __shared__ int s[64];
    int t = threadIdx.x;
    int v = (t < SCAN_NBLK) ? blocksums[t] : 0;
    s[t] = v;
    __syncthreads();
    #pragma unroll
    for (int off = 1; off < 64; off <<= 1) {
        int add = (t >= off) ? s[t - off] : 0;
        __syncthreads();
        s[t] += add;
        __syncthreads();
    }
    if (t < SCAN_NBLK) blockoffs[t] = s[t] - v;
    if (t == 63) row_start[NN] = s[63];
}

__global__ void scan_add(const int* __restrict__ excl, const int* __restrict__ blockoffs,
                         int* __restrict__ row_start, int* __restrict__ cursor)
{
    int i = blockIdx.x * 256 + threadIdx.x;
    if (i >= NN) return;
    int v = excl[i] + blockoffs[i >> 10];
    row_start[i] = v;
    cursor[i] = v;
}

// dst-range-partitioned scatter (single-XCD cursor/csr lines per partition)
__global__ __launch_bounds__(256) void scatter_part(const int* __restrict__ ei,
                                                    int* __restrict__ cursor,
                                                    ushort* __restrict__ csr_src)
{
    const int p = blockIdx.x & 7;
    const int q = blockIdx.x >> 3;
    const int nq = gridDim.x >> 3;
    const int lo = p * NPART, hi = lo + NPART;
    const int stride = nq * 256;
    for (int e = q * 256 + threadIdx.x; e < EE; e += stride) {
        int d = ei[EE + e];
        if (d >= lo && d < hi) {
            int s = ei[e];
            int pos = atomicAdd(&cursor[d], 1);
            csr_src[pos] = (ushort)s;
        }
    }
    for (int i = q * 256 + threadIdx.x; i < NPART; i += stride) {
        int d = lo + i;
        int pos = atomicAdd(&cursor[d], 1);
        csr_src[pos] = (ushort)d;
    }
}

// ---------------- MFMA node GEMM + fused attention coefficients ----------------
__global__ __launch_bounds__(256) void gemm_mfma(
    const ushort* __restrict__ Xb,   // [NN][128] bf16
    const ushort* __restrict__ Wt,   // [256][128] bf16
    const float* __restrict__ skb, const float* __restrict__ bb,
    const float* __restrict__ as_, const float* __restrict__ ad_,
    ushort* __restrict__ Hout, float* __restrict__ Agg,
    float* __restrict__ esrc, float* __restrict__ edst)
{
    __shared__ ushort Xs[64 * 128];          // 16 KB, XOR-swizzled rows
    __shared__ float sh_es[64][4], sh_ed[64][4];
    const int r0 = blockIdx.x * 64;
    const int tid = threadIdx.x;
    const int w = tid >> 6;
    const int l = tid & 63;
    const int lm = l & 15;
    const int lk = l >> 4;

    #pragma unroll
    for (int it = 0; it < 4; ++it) {
        int slot = it * 256 + tid;
        int row = slot >> 4;
        int bc = (slot & 15) << 4;
        int n = r0 + row;
        bf16x8 v = (bf16x8)(short)0;
        if (n < NN) v = *reinterpret_cast<const bf16x8*>(Xb + (size_t)n * 128 + (bc >> 1));
        *reinterpret_cast<bf16x8*>(reinterpret_cast<char*>(Xs) + row * 256 + (bc ^ ((row & 7) << 4))) = v;
    }
    __syncthreads();

    f32x4 acc[4][4];
    #pragma unroll
    for (int nb = 0; nb < 4; ++nb)
        #pragma unroll
        for (int rf = 0; rf < 4; ++rf)
            acc[nb][rf] = (f32x4){0.f, 0.f, 0.f, 0.f};

    #pragma unroll
    for (int ks = 0; ks < 4; ++ks) {
        bf16x8 a[4];
        #pragma unroll
        for (int rf = 0; rf < 4; ++rf) {
            int row = rf * 16 + lm;
            int bc = (ks * 32 + lk * 8) * 2;
            a[rf] = *reinterpret_cast<const bf16x8*>(
                reinterpret_cast<const char*>(Xs) + row * 256 + (bc ^ ((row & 7) << 4)));
        }
        #pragma unroll
        for (int nb = 0; nb < 4; ++nb) {
            int ncol = (w * 4 + nb) * 16 + lm;
            bf16x8 b = *reinterpret_cast<const bf16x8*>(Wt + (size_t)ncol * 128 + ks * 32 + lk * 8);
            #pragma unroll
            for (int rf = 0; rf < 4; ++rf)
                acc[nb][rf] = __builtin_amdgcn_mfma_f32_16x16x32_bf16(a[rf], b, acc[nb][rf], 0, 0, 0);
        }
    }

    if (w < 2) {
        float asv[4], adv[4];
        #pragma unroll
        for (int nb = 0; nb < 4; ++nb) {
            int ncol = (w * 4 + nb) * 16 + lm;
            asv[nb] = as_[ncol];
            adv[nb] = ad_[ncol];
        }
        #pragma unroll
        for (int rf = 0; rf < 4; ++rf) {
            #pragma unroll
            for (int r = 0; r < 4; ++r) {
                int nl = rf * 16 + lk * 4 + r;
                int n = r0 + nl;
                float es0 = 0.f, es1 = 0.f, ed0 = 0.f, ed1 = 0.f;
                #pragma unroll
                for (int nb = 0; nb < 4; ++nb) {
                    float v = acc[nb][rf][r];
                    int ncol = (w * 4 + nb) * 16 + lm;
                    if (n < NN) Hout[(size_t)n * 128 + ncol] = f2bf(v);
                    if (nb < 2) { es0 = fmaf(v, asv[nb], es0); ed0 = fmaf(v, adv[nb], ed0); }
                    else        { es1 = fmaf(v, asv[nb], es1); ed1 = fmaf(v, adv[nb], ed1); }
                }
                #pragma unroll
                for (int m = 1; m < 16; m <<= 1) {
                    es0 += __shfl_xor(es0, m); ed0 += __shfl_xor(ed0, m);
                    es1 += __shfl_xor(es1, m); ed1 += __shfl_xor(ed1, m);
                }
                if (lm == 0) {
                    sh_es[nl][w * 2 + 0] = es0; sh_ed[nl][w * 2 + 0] = ed0;
                    sh_es[nl][w * 2 + 1] = es1; sh_ed[nl][w * 2 + 1] = ed1;
                }
            }
        }
    } else {
        #pragma unroll
        for (int nb = 0; nb < 4; ++nb) {
            int ncol = (w * 4 + nb) * 16 + lm;
            int c = ncol - 128;
            #pragma unroll
            for (int rf = 0; rf < 4; ++rf) {
                #pragma unroll
                for (int r = 0; r < 4; ++r) {
                    int n = r0 + rf * 16 + lk * 4 + r;
                    if (n >= NN) continue;
                    Agg[(size_t)n * 128 + c] = acc[nb][rf][r] + skb[c] + bb[c];
                }
            }
        }
    }
    __syncthreads();
    if (tid < 256) {
        int nl = tid >> 2, hd = tid & 3;
        int n = r0 + nl;
        if (n < NN) {
            esrc[n * 4 + hd] = sh_es[nl][hd];
            edst[n * 4 + hd] = sh_ed[nl][hd];
        }
    }
}

// ---------------- fused per-dst softmax + aggregate + skip + relu (block per dst) ----------------
__global__ __launch_bounds__(128) void gat_aggr(
    const int* __restrict__ row_start, const ushort* __restrict__ csr_src,
    const float* __restrict__ esrc, const float* __restrict__ edst,
    const ushort* __restrict__ Hb, const float* __restrict__ skipagg,
    ushort* __restrict__ outbuf)
{
    __shared__ int   lsrc[CHUNK];
    __shared__ float lw[4][CPAD];
    __shared__ float shsc[4];
    __shared__ float accbuf[8][HCC];
    const int d = blockIdx.x;
    const int t = threadIdx.x;
    const int hd = t >> 5;
    const int l = t & 31;
    const int slot = t >> 4;
    const int cg = t & 15;
    const int c0 = cg * 8;
    const int ghd = cg >> 2;
    const int r0 = row_start[d], r1 = row_start[d + 1];
    const float4 edv = *reinterpret_cast<const float4*>(edst + (size_t)d * 4);
    float acc[8] = {0.f, 0.f, 0.f, 0.f, 0.f, 0.f, 0.f, 0.f};
    float m_h = -INFINITY, z_h = 0.f;

    for (int base = r0; base < r1; base += CHUNK) {
        const int nc = min(CHUNK, r1 - base);
        __syncthreads();
        for (int i = t; i < nc; i += 128) {
            int s = (int)csr_src[base + i];
            lsrc[i] = s;
            float4 ev = *reinterpret_cast<const float4*>(esrc + (size_t)s * 4);
            lw[0][i] = lrelu(ev.x + edv.x);
            lw[1][i] = lrelu(ev.y + edv.y);
            lw[2][i] = lrelu(ev.z + edv.z);
            lw[3][i] = lrelu(ev.w + edv.w);
        }
        __syncthreads();
        float mx = m_h;
        for (int i = l; i < nc; i += 32) mx = fmaxf(mx, lw[hd][i]);
        #pragma unroll
        for (int off = 16; off > 0; off >>= 1) mx = fmaxf(mx, __shfl_xor(mx, off, 32));
        float sc = __expf(m_h - mx);
        float zp = 0.f;
        for (int i = l; i < nc; i += 32) {
            float w = __expf(lw[hd][i] - mx);
            lw[hd][i] = w;
            zp += w;
        }
        #pragma unroll
        for (int off = 16; off > 0; off >>= 1) zp += __shfl_xor(zp, off, 32);
        z_h = z_h * sc + zp;
        m_h = mx;
        if (l == 0) shsc[hd] = sc;
        __syncthreads();
        float scg = shsc[ghd];
        #pragma unroll
        for (int j = 0; j < 8; ++j) acc[j] *= scg;
        for (int i = slot; i < nc; i += 8) {
            int s = lsrc[i];
            float wgt = lw[ghd][i];
            bf16x8 row = *reinterpret_cast<const bf16x8*>(Hb + (size_t)s * 128 + c0);
            #pragma unroll
            for (int j = 0; j < 8; ++j)
                acc[j] = fmaf(wgt, bf2f((ushort)row[j]), acc[j]);
        }
    }
    #pragma unroll
    for (int j = 0; j < 8; ++j) accbuf[slot][c0 + j] = acc[j];
    __syncthreads();
    float tot = 0.f;
    #pragma unroll
    for (int s = 0; s < 8; ++s) tot += accbuf[s][t];
    float res = skipagg[(size_t)d * 128 + t] + tot / z_h;
    outbuf[(size_t)d * 128 + t] = f2bf(fmaxf(res, 0.f));
}

// ---------------- pooling + fused MLP ----------------
__global__ __launch_bounds__(256) void pool_max_sorted(
    const ushort* __restrict__ xf, const int* __restrict__ batch,
    float* __restrict__ pooled)
{
    __shared__ int gb[32];
    const int n0 = blockIdx.x * 32;
    const int t = threadIdx.x;
    if (t < 32) gb[t] = (n0 + t < NN) ? batch[n0 + t] : -1;
    __syncthreads();
    const int c = t & 127;
    const int half = t >> 7;
    int curg = -1;
    float curv = -INFINITY;
    #pragma unroll 4
    for (int i = 0; i < 16; ++i) {
        int n = n0 + half * 16 + i;
        if (n >= NN) break;
        int g = gb[half * 16 + i];
        float v = bf2f(xf[(size_t)n * 128 + c]);
        if (g != curg) {
            if (curg >= 0) atomicMaxF(&pooled[curg * 128 + c], curv);
            curg = g; curv = v;
        } else {
            curv = fmaxf(curv, v);
        }
    }
    if (curg >= 0) atomicMaxF(&pooled[curg * 128 + c], curv);
}

__global__ __launch_bounds__(768) void mlp_fused(
    const float* __restrict__ pooled,
    const float* __restrict__ w1, const float* __restrict__ b1,
    const float* __restrict__ w2, const float* __restrict__ b2,
    float* __restrict__ out)
{
    __shared__ float xs[128];
    __shared__ float hs[NHIDD];
    int g = blockIdx.x, t = threadIdx.x;
    if (t < 128) {
        float v = pooled[g * 128 + t];
        if (!isfinite(v)) v = 0.f;
        xs[t] = v;
    }
    __syncthreads();
    if (t < NHIDD) {
        float acc = 0.f;
        #pragma unroll 8
        for (int k = 0; k < 128; ++k) acc += xs[k] * w1[(size_t)k * NHIDD + t];
        hs[t] = fmaxf(acc + b1[t], 0.f);
    }
    __syncthreads();
    float acc = 0.f;
    #pragma unroll 8
    for (int k = 0; k < NHIDD; ++k) acc += hs[k] * w2[(size_t)k * NOUTD + t];
    out[(size_t)g * NOUTD + t] = acc + b2[t];
}

extern "C" void kernel_launch(void* const* d_in, const int* in_sizes, int n_in,
                              void* d_out, int out_size, void* d_ws, size_t ws_size,
                              hipStream_t stream)
{
    const float* x = (const float*)d_in[0];
    const int* ei = (const int*)d_in[1];
    const int* batch = (const int*)d_in[2];
    const float* W[3]   = {(const float*)d_in[3],  (const float*)d_in[9],  (const float*)d_in[15]};
    const float* AS[3]  = {(const float*)d_in[4],  (const float*)d_in[10], (const float*)d_in[16]};
    const float* AD[3]  = {(const float*)d_in[5],  (const float*)d_in[11], (const float*)d_in[17]};
    const float* B[3]   = {(const float*)d_in[6],  (const float*)d_in[12], (const float*)d_in[18]};
    const float* SKW[3] = {(const float*)d_in[7],  (const float*)d_in[13], (const float*)d_in[19]};
    const float* SKB[3] = {(const float*)d_in[8],  (const float*)d_in[14], (const float*)d_in[20]};
    const float* m1w = (const float*)d_in[21];
    const float* m1b = (const float*)d_in[22];
    const float* m2w = (const float*)d_in[23];
    const float* m2b = (const float*)d_in[24];
    float* out = (float*)d_out;

    float* p = (float*)d_ws;
    ushort* bufA = (ushort*)p; p += (size_t)NN * HCC / 2;
    ushort* bufB = (ushort*)p; p += (size_t)NN * HCC / 2;
    ushort* xb   = (ushort*)p; p += (size_t)NN * HCC / 2;
    ushort* hbuf = (ushort*)p; p += (size_t)NN * HCC / 2;
    ushort* wt3  = (ushort*)p; p += 3 * 256 * 128 / 2;
    float* agg  = p; p += (size_t)NN * HCC;
    float* esrc = p; p += NN * 4;
    float* edst = p; p += NN * 4;
    float* pooled = p; p += GGR * HCC;
    int* cnt8      = (int*)p; p += NREP * NPAD;
    int* cursor    = (int*)p; p += NN;
    int* excl      = (int*)p; p += NN;
    int* row_start = (int*)p; p += NN + 4;
    ushort* csr_src = (ushort*)p; p += (EPE + 1) / 2;
    int* blocksums = (int*)p; p += 64;
    int* blockoffs = (int*)p; p += 64;

    prep<<<PREP_BLOCKS, 256, 0, stream>>>(x, xb, W[0], SKW[0], W[1], SKW[1], W[2], SKW[2],
                                          wt3, cnt8, pooled);
    hist8<<<(EPE + 255) / 256, 256, 0, stream>>>(ei, cnt8);
    scan_partial<<<SCAN_NBLK, 256, 0, stream>>>(cnt8, excl, blocksums);
    scan_sums<<<1, 64, 0, stream>>>(blocksums, blockoffs, row_start);
    scan_add<<<(NN + 255) / 256, 256, 0, stream>>>(excl, blockoffs, row_start, cursor);
    scatter_part<<<1024, 256, 0, stream>>>(ei, cursor, csr_src);

    const ushort* cur = xb;
    ushort* outs[3] = {bufA, bufB, bufA};
    for (int l = 0; l < 3; ++l) {
        gemm_mfma<<<MBLK, 256, 0, stream>>>(cur, wt3 + l * 256 * 128, SKB[l], B[l],
                                            AS[l], AD[l], hbuf, agg, esrc, edst);
        gat_aggr<<<NN, 128, 0, stream>>>(row_start, csr_src, esrc, edst, hbuf, agg, outs[l]);
        cur = outs[l];
    }
    pool_max_sorted<<<(NN + 31) / 32, 256, 0, stream>>>(cur, batch, pooled);
    mlp_fused<<<GGR, NOUTD, 0, stream>>>(pooled, m1w, m1b, m2w, m2b, out);
}